// Round 2
// baseline (1824.430 us; speedup 1.0000x reference)
//
#include <hip/hip_runtime.h>
#include <hip/hip_bf16.h>
#include <math.h>

typedef __hip_bfloat16 bf16;
typedef __attribute__((ext_vector_type(8))) __bf16 bf16x8;
typedef __attribute__((ext_vector_type(4))) float f32x4;

#define NN   4096
#define BB   8
#define DD   8
#define CC   64   // BB*DD
#define SS   16
#define KSUB 4
#define IND  16
#define HH   64
#define RDD  32

__device__ __forceinline__ float fsig(float x) {
    return __builtin_amdgcn_rcpf(1.f + __expf(-x));
}
__device__ __forceinline__ float ftanh(float x) {
    x = fminf(fmaxf(x, -15.f), 15.f);
    float e = __expf(2.f * x);
    return (e - 1.f) * __builtin_amdgcn_rcpf(e + 1.f);
}

// ---------------------------------------------------------------------------
// A (fp32) -> Ab (bf16), 8 elems/thread
// ---------------------------------------------------------------------------
__global__ __launch_bounds__(256) void k_convA(const float* __restrict__ A,
                                               bf16* __restrict__ Ab) {
    size_t i = ((size_t)blockIdx.x * 256 + threadIdx.x) * 8;
    float4 v0 = *reinterpret_cast<const float4*>(A + i);
    float4 v1 = *reinterpret_cast<const float4*>(A + i + 4);
    bf16 o[8];
    o[0] = __float2bfloat16(v0.x); o[1] = __float2bfloat16(v0.y);
    o[2] = __float2bfloat16(v0.z); o[3] = __float2bfloat16(v0.w);
    o[4] = __float2bfloat16(v1.x); o[5] = __float2bfloat16(v1.y);
    o[6] = __float2bfloat16(v1.z); o[7] = __float2bfloat16(v1.w);
    *reinterpret_cast<ulonglong2*>(&Ab[i]) = *reinterpret_cast<const ulonglong2*>(o);
}

// ---------------------------------------------------------------------------
// prep: traj[0] = h0 ; state = h0 + pert(x[0], h0)  (transposed layout [64][N])
// ---------------------------------------------------------------------------
__global__ __launch_bounds__(256) void k_prep(
    const float* __restrict__ h0, const float* __restrict__ x_all,
    const float* __restrict__ pW1, const float* __restrict__ pb1,
    const float* __restrict__ pW2, const float* __restrict__ pb2,
    float* __restrict__ hf_out, bf16* __restrict__ hb_out, float* __restrict__ traj)
{
    __shared__ float ls_pW1[24][64]; __shared__ float ls_pW2[64][9];
    __shared__ float ls_pb1[64];     __shared__ float ls_pb2[8];
    const int tid = threadIdx.x;
    for (int idx = tid; idx < 24*64; idx += 256) ls_pW1[idx>>6][idx&63] = pW1[idx];
    for (int idx = tid; idx < 64*8;  idx += 256) ls_pW2[idx>>3][idx&7]  = pW2[idx];
    if (tid < 64) ls_pb1[tid] = pb1[tid];
    else if (tid < 72) ls_pb2[tid-64] = pb2[tid-64];
    __syncthreads();

    const int gid = blockIdx.x * 256 + tid;   // row = b*NN + n
    const int b = gid >> 12, n = gid & (NN-1);
    float hv[8];
    const float* hp = h0 + (size_t)gid * 8;
#pragma unroll
    for (int d = 0; d < 8; ++d) { hv[d] = hp[d]; traj[(size_t)gid*8 + d] = hv[d]; }

    float xin[24];
    const float* xp = x_all + (size_t)gid * IND;   // s = 0
#pragma unroll
    for (int ii = 0; ii < 16; ++ii) xin[ii] = xp[ii];
#pragma unroll
    for (int d = 0; d < 8; ++d) xin[16+d] = hv[d];

    float ap[8] = {0,0,0,0,0,0,0,0};
    for (int j = 0; j < 64; ++j) {
        float s1 = ls_pb1[j];
#pragma unroll
        for (int ii = 0; ii < 24; ++ii) s1 += xin[ii] * ls_pW1[ii][j];
        s1 = fmaxf(s1, 0.f);
#pragma unroll
        for (int d = 0; d < 8; ++d) ap[d] += s1 * ls_pW2[j][d];
    }
#pragma unroll
    for (int d = 0; d < 8; ++d) {
        float hf_ = hv[d] + ap[d] + ls_pb2[d];
        hf_out[(size_t)(b*8+d)*NN + n] = hf_;
        hb_out[(size_t)(b*8+d)*NN + n] = __float2bfloat16(hf_);
    }
}

// ---------------------------------------------------------------------------
// substep: h_graph = A@h (MFMA), drift/diff MLPs, Euler update.
// k==3: write traj[s+1]; if s<14 fuse pert(x[s+1], h) into new state.
// ---------------------------------------------------------------------------
__global__ __launch_bounds__(512) void k_substep(
    const bf16* __restrict__ Ab,
    const bf16* __restrict__ hb_in, const float* __restrict__ hf_in,
    bf16* __restrict__ hb_out, float* __restrict__ hf_out,
    const float* __restrict__ times, const float* __restrict__ z_all,
    const float* __restrict__ x_all,
    const float* __restrict__ dW1, const float* __restrict__ db1,
    const float* __restrict__ dW2, const float* __restrict__ db2,
    const float* __restrict__ fW1, const float* __restrict__ fb1,
    const float* __restrict__ fW2, const float* __restrict__ fb2,
    const float* __restrict__ pW1, const float* __restrict__ pb1,
    const float* __restrict__ pW2, const float* __restrict__ pb2,
    float* __restrict__ traj, int s, int k)
{
    __shared__ float ls_part[8][16][65];   // per-wave K-chunk partial h_graph (33 KB)
    __shared__ float ls_hold[16][65];      // current h tile (4 KB)
    __shared__ float ls_dW1[9][64];  __shared__ float ls_dW2[64][9];
    __shared__ float ls_fW1[9][64];  __shared__ float ls_fW2[64][9];
    __shared__ float ls_db1[64];     __shared__ float ls_fb1[64];
    __shared__ float ls_db2[8];      __shared__ float ls_fb2[8];
    __shared__ float ls_pW1[24][64]; __shared__ float ls_pW2[64][9];
    __shared__ float ls_pb1[64];     __shared__ float ls_pb2[8];

    const int tid = threadIdx.x;
    const int wg  = blockIdx.x;                          // 256 WGs
    const int i0  = (((wg & 7) << 5) | (wg >> 3)) << 4;  // XCD-contiguous 16-node tile

    // stage weights (fp32)
    for (int idx = tid; idx < 9*64; idx += 512) { ls_dW1[idx>>6][idx&63] = dW1[idx]; ls_fW1[idx>>6][idx&63] = fW1[idx]; }
    for (int idx = tid; idx < 64*8; idx += 512) { ls_dW2[idx>>3][idx&7]  = dW2[idx]; ls_fW2[idx>>3][idx&7]  = fW2[idx]; }
    if (tid < 64) { ls_db1[tid] = db1[tid]; ls_fb1[tid] = fb1[tid]; }
    else if (tid < 72) { ls_db2[tid-64] = db2[tid-64]; ls_fb2[tid-64] = fb2[tid-64]; }
    const bool dopert = (k == 3) && (s < SS - 2);
    if (dopert) {
        for (int idx = tid; idx < 24*64; idx += 512) ls_pW1[idx>>6][idx&63] = pW1[idx];
        for (int idx = tid; idx < 64*8;  idx += 512) ls_pW2[idx>>3][idx&7]  = pW2[idx];
        if (tid < 64) ls_pb1[tid] = pb1[tid];
        else if (tid < 72) ls_pb2[tid-64] = pb2[tid-64];
    }
    { // stage h_old tile (fp32): ls_hold[node][c]
        int n = tid & 15, c0 = tid >> 4;
        ls_hold[n][c0]    = hf_in[(size_t)c0*NN + i0 + n];
        ls_hold[n][c0+32] = hf_in[(size_t)(c0+32)*NN + i0 + n];
    }

    const float t0 = times[s], t1 = times[s+1];
    const float dt = (t1 - t0) * 0.25f;
    const float tk = t0 + (float)k * dt;
    const float sqdt = sqrtf(dt);

    // ---- GEMM: D[c][i] = sum_j Ht[c][j] * A[i][j]; wave = 512-wide K chunk ----
    {
        const int wave = tid >> 6, lane = tid & 63;
        const int k0 = wave << 9;
        const int lrow = lane & 15, lkk = (lane >> 4) << 3;
        const bf16* pb = Ab    + (size_t)(i0 + lrow)*NN + k0 + lkk;  // A rows (B operand)
        const bf16* pa = hb_in + (size_t)lrow*NN        + k0 + lkk;  // Ht rows (A operand)
        f32x4 acc[4];
#pragma unroll
        for (int ct = 0; ct < 4; ++ct) acc[ct] = (f32x4){0.f,0.f,0.f,0.f};
#pragma unroll 4
        for (int kk = 0; kk < 16; ++kk) {
            bf16x8 bfr = *reinterpret_cast<const bf16x8*>(pb + kk*32);
#pragma unroll
            for (int ct = 0; ct < 4; ++ct) {
                bf16x8 afr = *reinterpret_cast<const bf16x8*>(pa + (size_t)ct*16*NN + kk*32);
                acc[ct] = __builtin_amdgcn_mfma_f32_16x16x32_bf16(afr, bfr, acc[ct], 0, 0, 0);
            }
        }
        const int rb = (lane >> 4) << 2;
#pragma unroll
        for (int ct = 0; ct < 4; ++ct)
#pragma unroll
            for (int r = 0; r < 4; ++r)
                ls_part[wave][lrow][ct*16 + rb + r] = acc[ct][r];
    }
    __syncthreads();

    // ---- per-(b,node) MLPs: 4 threads/row, 16 hidden units each ----
    const int q = tid & 3, row = tid >> 2;     // row 0..127
    const int node = row & 15, b = row >> 4;
    float ing[9], inh[9];
#pragma unroll
    for (int d = 0; d < 8; ++d) {
        float g = 0.f;
#pragma unroll
        for (int w = 0; w < 8; ++w) g += ls_part[w][node][b*8 + d];
        ing[d] = g;
        inh[d] = ls_hold[node][b*8 + d];
    }
    ing[8] = tk; inh[8] = tk;
    float adr[8] = {0,0,0,0,0,0,0,0}, adf[8] = {0,0,0,0,0,0,0,0};
    const int jb = q << 4;
#pragma unroll
    for (int jj = 0; jj < 16; ++jj) {
        int j = jb + jj;
        float s1 = ls_db1[j], s2 = ls_fb1[j];
#pragma unroll
        for (int d = 0; d < 9; ++d) { s1 += ing[d] * ls_dW1[d][j]; s2 += inh[d] * ls_fW1[d][j]; }
        float th = ftanh(s1), sg = fsig(s2);
#pragma unroll
        for (int d = 0; d < 8; ++d) { adr[d] += th * ls_dW2[j][d]; adf[d] += sg * ls_fW2[j][d]; }
    }
#pragma unroll
    for (int d = 0; d < 8; ++d) {
        adr[d] += __shfl_xor(adr[d], 1); adr[d] += __shfl_xor(adr[d], 2);
        adf[d] += __shfl_xor(adf[d], 1); adf[d] += __shfl_xor(adf[d], 2);
    }
    float hnew[2];
    const size_t zbase = ((size_t)((s*KSUB + k)*BB + b))*((size_t)NN*DD) + (size_t)(i0+node)*DD;
#pragma unroll
    for (int e = 0; e < 2; ++e) {
        int d = (q << 1) | e;
        float dr  = adr[d] + ls_db2[d];
        float df  = adf[d] + ls_fb2[d];
        float dif = 0.1f * fsig(df);
        float zz  = z_all[zbase + d];
        hnew[e] = inh[d] + dr * dt + dif * (sqdt * zz);
    }

    if (k < 3) {
#pragma unroll
        for (int e = 0; e < 2; ++e) {
            int d = (q << 1) | e; int c = b*8 + d;
            hf_out[(size_t)c*NN + i0 + node] = hnew[e];
            hb_out[(size_t)c*NN + i0 + node] = __float2bfloat16(hnew[e]);
        }
    } else {
        // traj[s+1] = h (pre-perturbation)
#pragma unroll
        for (int e = 0; e < 2; ++e) {
            int d = (q << 1) | e;
            traj[((size_t)((s+1)*BB + b))*((size_t)NN*DD) + (size_t)(i0+node)*DD + d] = hnew[e];
        }
        if (dopert) {
            __syncthreads();
#pragma unroll
            for (int e = 0; e < 2; ++e) { int d = (q << 1) | e; ls_part[0][node][b*8 + d] = hnew[e]; }
            __syncthreads();
            float xin[24];
            const float* xp = x_all + ((size_t)(s+1)*BB + b)*((size_t)NN*IND) + (size_t)(i0+node)*IND;
#pragma unroll
            for (int ii = 0; ii < 16; ++ii) xin[ii] = xp[ii];
#pragma unroll
            for (int d = 0; d < 8; ++d) xin[16+d] = ls_part[0][node][b*8 + d];
            float ap[8] = {0,0,0,0,0,0,0,0};
#pragma unroll
            for (int jj = 0; jj < 16; ++jj) {
                int j = jb + jj;
                float s1 = ls_pb1[j];
#pragma unroll
                for (int ii = 0; ii < 24; ++ii) s1 += xin[ii] * ls_pW1[ii][j];
                s1 = fmaxf(s1, 0.f);
#pragma unroll
                for (int d = 0; d < 8; ++d) ap[d] += s1 * ls_pW2[j][d];
            }
#pragma unroll
            for (int d = 0; d < 8; ++d) { ap[d] += __shfl_xor(ap[d], 1); ap[d] += __shfl_xor(ap[d], 2); }
#pragma unroll
            for (int e = 0; e < 2; ++e) {
                int d = (q << 1) | e; int c = b*8 + d;
                float hf_ = xin[16+d] + ap[d] + ls_pb2[d];
                hf_out[(size_t)c*NN + i0 + node] = hf_;
                hb_out[(size_t)c*NN + i0 + node] = __float2bfloat16(hf_);
            }
        } else {
#pragma unroll
            for (int e = 0; e < 2; ++e) {
                int d = (q << 1) | e; int c = b*8 + d;
                hf_out[(size_t)c*NN + i0 + node] = hnew[e];
                hb_out[(size_t)c*NN + i0 + node] = __float2bfloat16(hnew[e]);
            }
        }
    }
}

// ---------------------------------------------------------------------------
// readout: relu(traj @ rW1 + rb1) @ rW2 + rb2
// ---------------------------------------------------------------------------
__global__ __launch_bounds__(256) void k_readout(
    const float* __restrict__ traj,
    const float* __restrict__ rW1, const float* __restrict__ rb1,
    const float* __restrict__ rW2, const float* __restrict__ rb2,
    float* __restrict__ outr)
{
    __shared__ float ls_W1[8][64]; __shared__ float ls_W2[64][33];
    __shared__ float ls_b1[64];    __shared__ float ls_b2[32];
    const int tid = threadIdx.x;
    for (int idx = tid; idx < 8*64;  idx += 256) ls_W1[idx>>6][idx&63] = rW1[idx];
    for (int idx = tid; idx < 64*32; idx += 256) ls_W2[idx>>5][idx&31] = rW2[idx];
    if (tid < 64) ls_b1[tid] = rb1[tid];
    else if (tid < 96) ls_b2[tid-64] = rb2[tid-64];
    __syncthreads();

    const size_t gid = (size_t)blockIdx.x * 256 + tid;   // row over S*B*N
    float in[8];
    const float* ip = traj + gid * 8;
#pragma unroll
    for (int d = 0; d < 8; ++d) in[d] = ip[d];
    float out[32];
#pragma unroll
    for (int o = 0; o < 32; ++o) out[o] = ls_b2[o];
    for (int j = 0; j < 64; ++j) {
        float s1 = ls_b1[j];
#pragma unroll
        for (int d = 0; d < 8; ++d) s1 += in[d] * ls_W1[d][j];
        s1 = fmaxf(s1, 0.f);
#pragma unroll
        for (int o = 0; o < 32; ++o) out[o] += s1 * ls_W2[j][o];
    }
    float* op = outr + gid * 32;
#pragma unroll
    for (int o = 0; o < 32; ++o) op[o] = out[o];
}

// ---------------------------------------------------------------------------
extern "C" void kernel_launch(void* const* d_in, const int* in_sizes, int n_in,
                              void* d_out, int out_size, void* d_ws, size_t ws_size,
                              hipStream_t stream) {
    (void)in_sizes; (void)n_in; (void)out_size; (void)ws_size;
    const float* times = (const float*)d_in[0];
    const float* x_all = (const float*)d_in[1];
    const float* h0    = (const float*)d_in[2];
    const float* Amat  = (const float*)d_in[3];
    const float* z_all = (const float*)d_in[4];
    const float* dW1 = (const float*)d_in[5],  *db1 = (const float*)d_in[6];
    const float* dW2 = (const float*)d_in[7],  *db2 = (const float*)d_in[8];
    const float* fW1 = (const float*)d_in[9],  *fb1 = (const float*)d_in[10];
    const float* fW2 = (const float*)d_in[11], *fb2 = (const float*)d_in[12];
    const float* pW1 = (const float*)d_in[13], *pb1 = (const float*)d_in[14];
    const float* pW2 = (const float*)d_in[15], *pb2 = (const float*)d_in[16];
    const float* rW1 = (const float*)d_in[17], *rb1 = (const float*)d_in[18];
    const float* rW2 = (const float*)d_in[19], *rb2 = (const float*)d_in[20];

    float* traj = (float*)d_out;                      // [16,8,4096,8]
    float* outr = traj + (size_t)SS*BB*NN*DD;         // [16,8,4096,32]

    char* ws = (char*)d_ws;
    bf16*  Ab  = (bf16*)ws;                           // 32 MB
    float* hf0 = (float*)(ws + (34u << 20));
    float* hf1 = (float*)(ws + (35u << 20));
    bf16*  hb0 = (bf16*)(ws + (36u << 20));
    bf16*  hb1 = (bf16*)(ws + (36u << 20) + (1u << 19));
    float* hf[2] = {hf0, hf1};
    bf16*  hb[2] = {hb0, hb1};

    k_convA<<<NN*NN/(256*8), 256, 0, stream>>>(Amat, Ab);
    k_prep<<<BB*NN/256, 256, 0, stream>>>(h0, x_all, pW1, pb1, pW2, pb2,
                                          hf[0], hb[0], traj);
    for (int s = 0; s < SS - 1; ++s) {
        for (int k = 0; k < KSUB; ++k) {
            int g = s * KSUB + k;
            int rbuf = g & 1, wbuf = rbuf ^ 1;
            k_substep<<<NN/16, 512, 0, stream>>>(
                Ab, hb[rbuf], hf[rbuf], hb[wbuf], hf[wbuf],
                times, z_all, x_all,
                dW1, db1, dW2, db2, fW1, fb1, fW2, fb2,
                pW1, pb1, pW2, pb2, traj, s, k);
        }
    }
    k_readout<<<(SS*BB*NN)/256, 256, 0, stream>>>(traj, rW1, rb1, rW2, rb2, outr);
}

// Round 3
// 1775.875 us; speedup vs baseline: 1.0273x; 1.0273x over previous
//
#include <hip/hip_runtime.h>
#include <hip/hip_bf16.h>
#include <math.h>

typedef __hip_bfloat16 bf16;
typedef __attribute__((ext_vector_type(8))) __bf16 bf16x8;
typedef __attribute__((ext_vector_type(4))) float f32x4;

#define NN   4096
#define BB   8
#define DD   8
#define CC   64   // BB*DD
#define SS   16
#define KSUB 4
#define IND  16
#define HH   64
#define RDD  32

__device__ __forceinline__ float fsig(float x) {
    return __builtin_amdgcn_rcpf(1.f + __expf(-x));
}
__device__ __forceinline__ float ftanh(float x) {
    x = fminf(fmaxf(x, -15.f), 15.f);
    float e = __expf(2.f * x);
    return (e - 1.f) * __builtin_amdgcn_rcpf(e + 1.f);
}

// ---------------------------------------------------------------------------
// A (fp32) -> Ab (bf16), 8 elems/thread
// ---------------------------------------------------------------------------
__global__ __launch_bounds__(256) void k_convA(const float* __restrict__ A,
                                               bf16* __restrict__ Ab) {
    size_t i = ((size_t)blockIdx.x * 256 + threadIdx.x) * 8;
    float4 v0 = *reinterpret_cast<const float4*>(A + i);
    float4 v1 = *reinterpret_cast<const float4*>(A + i + 4);
    bf16 o[8];
    o[0] = __float2bfloat16(v0.x); o[1] = __float2bfloat16(v0.y);
    o[2] = __float2bfloat16(v0.z); o[3] = __float2bfloat16(v0.w);
    o[4] = __float2bfloat16(v1.x); o[5] = __float2bfloat16(v1.y);
    o[6] = __float2bfloat16(v1.z); o[7] = __float2bfloat16(v1.w);
    *reinterpret_cast<ulonglong2*>(&Ab[i]) = *reinterpret_cast<const ulonglong2*>(o);
}

// ---------------------------------------------------------------------------
// prep: traj[0] = h0 ; state = h0 + pert(x[0], h0)  (transposed layout [64][N])
// ---------------------------------------------------------------------------
__global__ __launch_bounds__(256) void k_prep(
    const float* __restrict__ h0, const float* __restrict__ x_all,
    const float* __restrict__ pW1, const float* __restrict__ pb1,
    const float* __restrict__ pW2, const float* __restrict__ pb2,
    float* __restrict__ hf_out, bf16* __restrict__ hb_out, float* __restrict__ traj)
{
    __shared__ float ls_pW1[24][64]; __shared__ float ls_pW2[64][9];
    __shared__ float ls_pb1[64];     __shared__ float ls_pb2[8];
    const int tid = threadIdx.x;
    for (int idx = tid; idx < 24*64; idx += 256) ls_pW1[idx>>6][idx&63] = pW1[idx];
    for (int idx = tid; idx < 64*8;  idx += 256) ls_pW2[idx>>3][idx&7]  = pW2[idx];
    if (tid < 64) ls_pb1[tid] = pb1[tid];
    else if (tid < 72) ls_pb2[tid-64] = pb2[tid-64];
    __syncthreads();

    const int gid = blockIdx.x * 256 + tid;   // row = b*NN + n
    const int b = gid >> 12, n = gid & (NN-1);
    float hv[8];
    const float* hp = h0 + (size_t)gid * 8;
#pragma unroll
    for (int d = 0; d < 8; ++d) { hv[d] = hp[d]; traj[(size_t)gid*8 + d] = hv[d]; }

    float xin[24];
    const float* xp = x_all + (size_t)gid * IND;   // s = 0
#pragma unroll
    for (int ii = 0; ii < 16; ++ii) xin[ii] = xp[ii];
#pragma unroll
    for (int d = 0; d < 8; ++d) xin[16+d] = hv[d];

    float ap[8] = {0,0,0,0,0,0,0,0};
    for (int j = 0; j < 64; ++j) {
        float s1 = ls_pb1[j];
#pragma unroll
        for (int ii = 0; ii < 24; ++ii) s1 += xin[ii] * ls_pW1[ii][j];
        s1 = fmaxf(s1, 0.f);
#pragma unroll
        for (int d = 0; d < 8; ++d) ap[d] += s1 * ls_pW2[j][d];
    }
#pragma unroll
    for (int d = 0; d < 8; ++d) {
        float hf_ = hv[d] + ap[d] + ls_pb2[d];
        hf_out[(size_t)(b*8+d)*NN + n] = hf_;
        hb_out[(size_t)(b*8+d)*NN + n] = __float2bfloat16(hf_);
    }
}

// ---------------------------------------------------------------------------
// substep (1024 thr, 16 waves): h_graph = A@h (MFMA, K-chunk 256/wave),
// 2-stage LDS reduce, then drift/diff MLPs + Euler; k==3 writes traj,
// s<14 fuses pert.
// ---------------------------------------------------------------------------
__global__ __launch_bounds__(1024, 4) void k_substep(
    const bf16* __restrict__ Ab,
    const bf16* __restrict__ hb_in, const float* __restrict__ hf_in,
    bf16* __restrict__ hb_out, float* __restrict__ hf_out,
    const float* __restrict__ times, const float* __restrict__ z_all,
    const float* __restrict__ x_all,
    const float* __restrict__ dW1, const float* __restrict__ db1,
    const float* __restrict__ dW2, const float* __restrict__ db2,
    const float* __restrict__ fW1, const float* __restrict__ fb1,
    const float* __restrict__ fW2, const float* __restrict__ fb2,
    const float* __restrict__ pW1, const float* __restrict__ pb1,
    const float* __restrict__ pW2, const float* __restrict__ pb2,
    float* __restrict__ traj, int s, int k)
{
    __shared__ float ls_part[8][16][68];    // 34.8 KB, rows 16B-aligned
    __shared__ float ls_hold[16][68];       // 4.35 KB
    __shared__ float ls_dW1T[64][12]; __shared__ float ls_fW1T[64][12];  // [j][d], d=0..8
    __shared__ float ls_dW2[64][8];   __shared__ float ls_fW2[64][8];    // [j][d]
    __shared__ float ls_pW1T[64][24]; __shared__ float ls_pW2[64][8];
    __shared__ float ls_db1[64];      __shared__ float ls_fb1[64];
    __shared__ float ls_pb1[64];
    __shared__ float ls_db2[8];  __shared__ float ls_fb2[8];  __shared__ float ls_pb2[8];

    const int tid = threadIdx.x;
    const int wg  = blockIdx.x;                          // 256 WGs
    const int i0  = (((wg & 7) << 5) | (wg >> 3)) << 4;  // XCD-contiguous 16-node tile

    // stage weights transposed
    for (int idx = tid; idx < 9*64; idx += 1024) {
        int d = idx >> 6, j = idx & 63;
        ls_dW1T[j][d] = dW1[idx]; ls_fW1T[j][d] = fW1[idx];
    }
    for (int idx = tid; idx < 64*8; idx += 1024) {
        ls_dW2[idx>>3][idx&7] = dW2[idx]; ls_fW2[idx>>3][idx&7] = fW2[idx];
    }
    if (tid < 64) { ls_db1[tid] = db1[tid]; ls_fb1[tid] = fb1[tid]; }
    else if (tid < 72) { ls_db2[tid-64] = db2[tid-64]; ls_fb2[tid-64] = fb2[tid-64]; }
    const bool dopert = (k == 3) && (s < SS - 2);
    if (dopert) {
        for (int idx = tid; idx < 24*64; idx += 1024) ls_pW1T[idx&63][idx>>6] = pW1[idx];
        for (int idx = tid; idx < 64*8;  idx += 1024) ls_pW2[idx>>3][idx&7]   = pW2[idx];
        if (tid < 64) ls_pb1[tid] = pb1[tid];
        else if (tid < 72) ls_pb2[tid-64] = pb2[tid-64];
    }
    { // stage h_old tile: ls_hold[node][c]
        int n = tid & 15, c0 = tid >> 4;      // c0 = 0..63
        ls_hold[n][c0] = hf_in[(size_t)c0*NN + i0 + n];
    }

    const float t0 = times[s], t1 = times[s+1];
    const float dt = (t1 - t0) * 0.25f;
    const float tk = t0 + (float)k * dt;
    const float sqdt = sqrtf(dt);

    // ---- GEMM: D[c][node] partials; wave = 256-wide K chunk ----
    {
        const int wave = tid >> 6, lane = tid & 63;
        const int k0 = wave << 8;
        const int lrow = lane & 15, lkk = (lane >> 4) << 3;
        const bf16* pb = Ab    + (size_t)(i0 + lrow)*NN + k0 + lkk;  // A rows (B op)
        const bf16* pa = hb_in + (size_t)lrow*NN        + k0 + lkk;  // Ht rows (A op)
        f32x4 acc[4];
#pragma unroll
        for (int ct = 0; ct < 4; ++ct) acc[ct] = (f32x4){0.f,0.f,0.f,0.f};
#pragma unroll 4
        for (int kk = 0; kk < 8; ++kk) {
            bf16x8 bfr = *reinterpret_cast<const bf16x8*>(pb + kk*32);
#pragma unroll
            for (int ct = 0; ct < 4; ++ct) {
                bf16x8 afr = *reinterpret_cast<const bf16x8*>(pa + ct*16*NN + kk*32);
                acc[ct] = __builtin_amdgcn_mfma_f32_16x16x32_bf16(afr, bfr, acc[ct], 0, 0, 0);
            }
        }
        const int rb = (lane >> 4) << 2;
        if (wave < 8) {
#pragma unroll
            for (int ct = 0; ct < 4; ++ct)
#pragma unroll
                for (int r = 0; r < 4; ++r)
                    ls_part[wave][lrow][ct*16 + rb + r] = acc[ct][r];
        }
        __syncthreads();
        if (wave >= 8) {
#pragma unroll
            for (int ct = 0; ct < 4; ++ct)
#pragma unroll
                for (int r = 0; r < 4; ++r)
                    ls_part[wave-8][lrow][ct*16 + rb + r] += acc[ct][r];
        }
        __syncthreads();
    }

    // ---- per-(b,node) MLPs: 8 threads/row, interleaved j = q + 8*jj ----
    const int q = tid & 7, row = tid >> 3;     // row 0..127
    const int node = row & 15, b = row >> 4;
    float ing[9], inh[9];
    {
        f32x4 g0 = (f32x4){0,0,0,0}, g1 = (f32x4){0,0,0,0};
#pragma unroll
        for (int w = 0; w < 8; ++w) {
            g0 += *reinterpret_cast<const f32x4*>(&ls_part[w][node][b*8]);
            g1 += *reinterpret_cast<const f32x4*>(&ls_part[w][node][b*8+4]);
        }
        f32x4 h0v = *reinterpret_cast<const f32x4*>(&ls_hold[node][b*8]);
        f32x4 h1v = *reinterpret_cast<const f32x4*>(&ls_hold[node][b*8+4]);
#pragma unroll
        for (int r = 0; r < 4; ++r) {
            ing[r] = g0[r]; ing[4+r] = g1[r];
            inh[r] = h0v[r]; inh[4+r] = h1v[r];
        }
    }
    ing[8] = tk; inh[8] = tk;
    float adr[8] = {0,0,0,0,0,0,0,0}, adf[8] = {0,0,0,0,0,0,0,0};
#pragma unroll
    for (int jj = 0; jj < 8; ++jj) {
        const int j = q + (jj << 3);
        f32x4 w1a = *reinterpret_cast<const f32x4*>(&ls_dW1T[j][0]);
        f32x4 w1b = *reinterpret_cast<const f32x4*>(&ls_dW1T[j][4]);
        float w1t = ls_dW1T[j][8];
        f32x4 v1a = *reinterpret_cast<const f32x4*>(&ls_fW1T[j][0]);
        f32x4 v1b = *reinterpret_cast<const f32x4*>(&ls_fW1T[j][4]);
        float v1t = ls_fW1T[j][8];
        float s1 = ls_db1[j], s2 = ls_fb1[j];
#pragma unroll
        for (int r = 0; r < 4; ++r) {
            s1 += ing[r]*w1a[r] + ing[4+r]*w1b[r];
            s2 += inh[r]*v1a[r] + inh[4+r]*v1b[r];
        }
        s1 += ing[8]*w1t; s2 += inh[8]*v1t;
        float th = ftanh(s1), sg = fsig(s2);
        f32x4 w2a = *reinterpret_cast<const f32x4*>(&ls_dW2[j][0]);
        f32x4 w2b = *reinterpret_cast<const f32x4*>(&ls_dW2[j][4]);
        f32x4 v2a = *reinterpret_cast<const f32x4*>(&ls_fW2[j][0]);
        f32x4 v2b = *reinterpret_cast<const f32x4*>(&ls_fW2[j][4]);
#pragma unroll
        for (int r = 0; r < 4; ++r) {
            adr[r] += th*w2a[r]; adr[4+r] += th*w2b[r];
            adf[r] += sg*v2a[r]; adf[4+r] += sg*v2b[r];
        }
    }
#pragma unroll
    for (int d = 0; d < 8; ++d) {
        adr[d] += __shfl_xor(adr[d], 1); adr[d] += __shfl_xor(adr[d], 2); adr[d] += __shfl_xor(adr[d], 4);
        adf[d] += __shfl_xor(adf[d], 1); adf[d] += __shfl_xor(adf[d], 2); adf[d] += __shfl_xor(adf[d], 4);
    }
    // every lane of a row now has full sums; compute all 8 hnew
    const size_t zbase = ((size_t)((s*KSUB + k)*BB + b))*((size_t)NN*DD) + (size_t)(i0+node)*DD;
    float4 z0 = *reinterpret_cast<const float4*>(z_all + zbase);
    float4 z1 = *reinterpret_cast<const float4*>(z_all + zbase + 4);
    float zz[8] = {z0.x, z0.y, z0.z, z0.w, z1.x, z1.y, z1.z, z1.w};
    float hnew[8];
#pragma unroll
    for (int d = 0; d < 8; ++d) {
        float dr  = adr[d] + ls_db2[d];
        float dif = 0.1f * fsig(adf[d] + ls_fb2[d]);
        hnew[d] = inh[d] + dr * dt + dif * (sqdt * zz[d]);
    }

    if (k == 3) {
        // traj[s+1] = h (pre-perturbation): thread writes its d=q element
        traj[((size_t)((s+1)*BB + b))*((size_t)NN*DD) + (size_t)(i0+node)*DD + q] = hnew[q];
    }
    float outv;
    if (dopert) {
        float xin[24];
        const float* xp = x_all + ((size_t)(s+1)*BB + b)*((size_t)NN*IND) + (size_t)(i0+node)*IND;
        float4 x0 = *reinterpret_cast<const float4*>(xp);
        float4 x1 = *reinterpret_cast<const float4*>(xp + 4);
        float4 x2 = *reinterpret_cast<const float4*>(xp + 8);
        float4 x3 = *reinterpret_cast<const float4*>(xp + 12);
        xin[0]=x0.x; xin[1]=x0.y; xin[2]=x0.z; xin[3]=x0.w;
        xin[4]=x1.x; xin[5]=x1.y; xin[6]=x1.z; xin[7]=x1.w;
        xin[8]=x2.x; xin[9]=x2.y; xin[10]=x2.z; xin[11]=x2.w;
        xin[12]=x3.x; xin[13]=x3.y; xin[14]=x3.z; xin[15]=x3.w;
#pragma unroll
        for (int d = 0; d < 8; ++d) xin[16+d] = hnew[d];
        float ap[8] = {0,0,0,0,0,0,0,0};
#pragma unroll
        for (int jj = 0; jj < 8; ++jj) {
            const int j = q + (jj << 3);
            float s1 = ls_pb1[j];
#pragma unroll
            for (int c4 = 0; c4 < 6; ++c4) {
                f32x4 wv = *reinterpret_cast<const f32x4*>(&ls_pW1T[j][c4*4]);
#pragma unroll
                for (int r = 0; r < 4; ++r) s1 += xin[c4*4+r] * wv[r];
            }
            s1 = fmaxf(s1, 0.f);
            f32x4 w2a = *reinterpret_cast<const f32x4*>(&ls_pW2[j][0]);
            f32x4 w2b = *reinterpret_cast<const f32x4*>(&ls_pW2[j][4]);
#pragma unroll
            for (int r = 0; r < 4; ++r) { ap[r] += s1*w2a[r]; ap[4+r] += s1*w2b[r]; }
        }
        float apq = ap[q];
        apq += __shfl_xor(apq, 1); apq += __shfl_xor(apq, 2); apq += __shfl_xor(apq, 4);
        // careful: shfl of ap[q] mixes different d across lanes — do full butterfly instead
        // (recompute properly below)
        float aps[8];
#pragma unroll
        for (int d = 0; d < 8; ++d) {
            float v = ap[d];
            v += __shfl_xor(v, 1); v += __shfl_xor(v, 2); v += __shfl_xor(v, 4);
            aps[d] = v;
        }
        outv = hnew[q] + aps[q] + ls_pb2[q];
    } else {
        outv = hnew[q];
    }
    {
        const int c = b*8 + q;
        hf_out[(size_t)c*NN + i0 + node] = outv;
        hb_out[(size_t)c*NN + i0 + node] = __float2bfloat16(outv);
    }
}

// ---------------------------------------------------------------------------
// readout: relu(traj @ rW1 + rb1) @ rW2 + rb2 ; 2 rows/thread
// ---------------------------------------------------------------------------
__global__ __launch_bounds__(256) void k_readout(
    const float* __restrict__ traj,
    const float* __restrict__ rW1, const float* __restrict__ rb1,
    const float* __restrict__ rW2, const float* __restrict__ rb2,
    float* __restrict__ outr)
{
    __shared__ float ls_W1T[64][12];   // [j][d]
    __shared__ float ls_W2[64][32];
    __shared__ float ls_b1[64];    __shared__ float ls_b2[32];
    const int tid = threadIdx.x;
    for (int idx = tid; idx < 8*64;  idx += 256) ls_W1T[idx&63][idx>>6] = rW1[idx];
    for (int idx = tid; idx < 64*32; idx += 256) ls_W2[idx>>5][idx&31] = rW2[idx];
    if (tid < 64) ls_b1[tid] = rb1[tid];
    else if (tid < 96) ls_b2[tid-64] = rb2[tid-64];
    __syncthreads();

    const size_t r0 = ((size_t)blockIdx.x * 256 + tid) * 2;   // 2 adjacent rows
    float ina[8], inb[8];
    {
        const float4* pa = reinterpret_cast<const float4*>(traj + r0*8);
        float4 a0 = pa[0], a1 = pa[1], b0 = pa[2], b1 = pa[3];
        ina[0]=a0.x; ina[1]=a0.y; ina[2]=a0.z; ina[3]=a0.w;
        ina[4]=a1.x; ina[5]=a1.y; ina[6]=a1.z; ina[7]=a1.w;
        inb[0]=b0.x; inb[1]=b0.y; inb[2]=b0.z; inb[3]=b0.w;
        inb[4]=b1.x; inb[5]=b1.y; inb[6]=b1.z; inb[7]=b1.w;
    }
    float outa[32], outb[32];
#pragma unroll
    for (int o = 0; o < 32; ++o) { outa[o] = ls_b2[o]; outb[o] = ls_b2[o]; }
    for (int j = 0; j < 64; ++j) {
        f32x4 w1a = *reinterpret_cast<const f32x4*>(&ls_W1T[j][0]);
        f32x4 w1b = *reinterpret_cast<const f32x4*>(&ls_W1T[j][4]);
        float sa = ls_b1[j], sb = sa;
#pragma unroll
        for (int r = 0; r < 4; ++r) {
            sa += ina[r]*w1a[r] + ina[4+r]*w1b[r];
            sb += inb[r]*w1a[r] + inb[4+r]*w1b[r];
        }
        sa = fmaxf(sa, 0.f); sb = fmaxf(sb, 0.f);
#pragma unroll
        for (int o4 = 0; o4 < 8; ++o4) {
            f32x4 w2 = *reinterpret_cast<const f32x4*>(&ls_W2[j][o4*4]);
#pragma unroll
            for (int r = 0; r < 4; ++r) {
                outa[o4*4+r] += sa * w2[r];
                outb[o4*4+r] += sb * w2[r];
            }
        }
    }
    float* op = outr + r0 * 32;
#pragma unroll
    for (int o4 = 0; o4 < 8; ++o4) {
        float4 va = {outa[o4*4], outa[o4*4+1], outa[o4*4+2], outa[o4*4+3]};
        float4 vb = {outb[o4*4], outb[o4*4+1], outb[o4*4+2], outb[o4*4+3]};
        *reinterpret_cast<float4*>(op + o4*4)      = va;
        *reinterpret_cast<float4*>(op + 32 + o4*4) = vb;
    }
}

// ---------------------------------------------------------------------------
extern "C" void kernel_launch(void* const* d_in, const int* in_sizes, int n_in,
                              void* d_out, int out_size, void* d_ws, size_t ws_size,
                              hipStream_t stream) {
    (void)in_sizes; (void)n_in; (void)out_size; (void)ws_size;
    const float* times = (const float*)d_in[0];
    const float* x_all = (const float*)d_in[1];
    const float* h0    = (const float*)d_in[2];
    const float* Amat  = (const float*)d_in[3];
    const float* z_all = (const float*)d_in[4];
    const float* dW1 = (const float*)d_in[5],  *db1 = (const float*)d_in[6];
    const float* dW2 = (const float*)d_in[7],  *db2 = (const float*)d_in[8];
    const float* fW1 = (const float*)d_in[9],  *fb1 = (const float*)d_in[10];
    const float* fW2 = (const float*)d_in[11], *fb2 = (const float*)d_in[12];
    const float* pW1 = (const float*)d_in[13], *pb1 = (const float*)d_in[14];
    const float* pW2 = (const float*)d_in[15], *pb2 = (const float*)d_in[16];
    const float* rW1 = (const float*)d_in[17], *rb1 = (const float*)d_in[18];
    const float* rW2 = (const float*)d_in[19], *rb2 = (const float*)d_in[20];

    float* traj = (float*)d_out;                      // [16,8,4096,8]
    float* outr = traj + (size_t)SS*BB*NN*DD;         // [16,8,4096,32]

    char* ws = (char*)d_ws;
    bf16*  Ab  = (bf16*)ws;                           // 32 MB
    float* hf0 = (float*)(ws + (34u << 20));
    float* hf1 = (float*)(ws + (35u << 20));
    bf16*  hb0 = (bf16*)(ws + (36u << 20));
    bf16*  hb1 = (bf16*)(ws + (36u << 20) + (1u << 19));
    float* hf[2] = {hf0, hf1};
    bf16*  hb[2] = {hb0, hb1};

    k_convA<<<NN*NN/(256*8), 256, 0, stream>>>(Amat, Ab);
    k_prep<<<BB*NN/256, 256, 0, stream>>>(h0, x_all, pW1, pb1, pW2, pb2,
                                          hf[0], hb[0], traj);
    for (int s = 0; s < SS - 1; ++s) {
        for (int k = 0; k < KSUB; ++k) {
            int g = s * KSUB + k;
            int rbuf = g & 1, wbuf = rbuf ^ 1;
            k_substep<<<NN/16, 1024, 0, stream>>>(
                Ab, hb[rbuf], hf[rbuf], hb[wbuf], hf[wbuf],
                times, z_all, x_all,
                dW1, db1, dW2, db2, fW1, fb1, fW2, fb2,
                pW1, pb1, pW2, pb2, traj, s, k);
        }
    }
    k_readout<<<(SS*BB*NN)/512, 256, 0, stream>>>(traj, rW1, rb1, rW2, rb2, outr);
}